// Round 1
// baseline (140.891 us; speedup 1.0000x reference)
//
#include <hip/hip_runtime.h>
#include <math.h>

// GATConv (PyG 1.3.2), H=1, IN=C=128. 3 dispatches:
//  k1 wtzero: W -> bf16 W^T (padded) + zero gcur
//  k2 gemm_scatter: heterogeneous grid — blocks [0,sb): bucket-scatter (LDS stash);
//                   blocks [sb,sb+gb): MFMA bf16 gemm, x-tile LDS-staged (coalesced),
//                   2 row-tiles per block (128 rows)
//  k3 aggregate: per-bucket LDS counting sort; p=exp(leaky(alpha)) without max-shift
//                (alpha bounded, softmax invariant to common factor); pair-gather:
//                dwordx2 loads, 2 edges per instruction (32 lanes/edge), pad-8,
//                ssum accumulated in sort phase via LDS float atomics.

constexpr int CH = 128;
constexpr int BNODES = 64;     // dst nodes per bucket
constexpr int CAP = 2048;      // max edges per bucket (avg ~1088)
constexpr int SCAP = 3072;     // CAP + 64*8 pad headroom (2560) rounded up
constexpr int NBMAX = 1024;    // supports N <= 65536
constexpr int SCHUNK = 4096;   // edges per scatter block
constexpr int WTS = 136;       // padded row stride in bf16 (16B-aligned; b128 reads uniform)
constexpr unsigned SENT = 0xFFFFFFFFu;

typedef __attribute__((ext_vector_type(8))) short bf16x8;
typedef __attribute__((ext_vector_type(4))) float f32x4;

static __device__ __forceinline__ unsigned short f2bf(float f) {
    unsigned u = __float_as_uint(f);
    unsigned r = (u + 0x7fffu + ((u >> 16) & 1u)) >> 16;   // RNE
    return (unsigned short)r;
}

// W[128][128] fp32 -> WT[n][k] bf16 (stride WTS) + zero gcur. Grid 8 x 256.
__global__ __launch_bounds__(256) void wtzero_kernel(const float* __restrict__ W,
                                                     unsigned short* __restrict__ WT,
                                                     int* __restrict__ gcur, int nb) {
    const int T = blockIdx.x * 256 + threadIdx.x;   // 0..2047
    if (T < nb) gcur[T] = 0;
    const int k = T >> 4;
    const int n8 = (T & 15) * 8;
    const float4 a = *(const float4*)&W[k * CH + n8];
    const float4 b = *(const float4*)&W[k * CH + n8 + 4];
    WT[(n8 + 0) * WTS + k] = f2bf(a.x);
    WT[(n8 + 1) * WTS + k] = f2bf(a.y);
    WT[(n8 + 2) * WTS + k] = f2bf(a.z);
    WT[(n8 + 3) * WTS + k] = f2bf(a.w);
    WT[(n8 + 4) * WTS + k] = f2bf(b.x);
    WT[(n8 + 5) * WTS + k] = f2bf(b.y);
    WT[(n8 + 6) * WTS + k] = f2bf(b.z);
    WT[(n8 + 7) * WTS + k] = f2bf(b.w);
}

// Heterogeneous: blocks [0,sb) scatter, [sb,sb+gb) gemm (2x64-row tiles). 256 thr.
__global__ __launch_bounds__(256) void gemm_scatter_kernel(const float* __restrict__ x,
                                                           const unsigned short* __restrict__ WT,
                                                           const float* __restrict__ att,
                                                           unsigned short* __restrict__ hb,
                                                           float* __restrict__ ad,
                                                           float* __restrict__ as_,
                                                           const int* __restrict__ src,
                                                           const int* __restrict__ dst,
                                                           int* __restrict__ gcur,
                                                           unsigned* __restrict__ recs,
                                                           int n, int etot, int nb, int sb) {
    __shared__ alignas(16) unsigned char smem[52224];   // WT 34816 + Xs 17408
    const int tid = threadIdx.x;

    if ((int)blockIdx.x >= sb) {
        // ------- GEMM branch: 128 rows = 2 x-tiles; WT + x-tile staged in LDS -------
        unsigned short* Wl = (unsigned short*)smem;                  // 34816 B
        unsigned short* Xs = (unsigned short*)(smem + 34816);        // 64 x WTS bf16
        {
            const uint4* s = (const uint4*)WT;
            uint4* d = (uint4*)Wl;
            for (int i = tid; i < CH * WTS / 8; i += 256) d[i] = s[i];
        }

        const int lane = tid & 63, wave = tid >> 6;
        const int m = lane & 15, quad = lane >> 4;
        const int tbase = ((int)blockIdx.x - sb) * 128;
        // x staging map: 4 threads per row, interleaved float4s (coalesced 64B/4thr)
        const int srow = tid >> 2, sseg = tid & 3;

        #pragma unroll 1
        for (int half = 0; half < 2; ++half) {
            __syncthreads();   // protect Xs (and cover initial Wl stage)
            {
                const int grow = min(tbase + half * 64 + srow, n - 1);
                const float* gx = x + (size_t)grow * CH;
                unsigned short* xd = &Xs[srow * WTS];
                #pragma unroll
                for (int i = 0; i < 8; ++i) {
                    const int c = sseg * 4 + i * 16;
                    const float4 u = *(const float4*)&gx[c];
                    ushort4 hs;
                    hs.x = f2bf(u.x); hs.y = f2bf(u.y); hs.z = f2bf(u.z); hs.w = f2bf(u.w);
                    *(ushort4*)&xd[c] = hs;
                }
            }
            __syncthreads();

            const int row0 = tbase + half * 64 + wave * 16;
            f32x4 acc[8] = {};
            #pragma unroll
            for (int t = 0; t < 4; ++t) {
                const int kb = t * 32 + quad * 8;
                const bf16x8 afr = *(const bf16x8*)&Xs[(wave * 16 + m) * WTS + kb];
                #pragma unroll
                for (int nt = 0; nt < 8; ++nt) {
                    const bf16x8 bfr = *(const bf16x8*)&Wl[(nt * 16 + m) * WTS + kb];
                    acc[nt] = __builtin_amdgcn_mfma_f32_16x16x32_bf16(afr, bfr, acc[nt], 0, 0, 0);
                }
            }

            const int rbase = row0 + quad * 4;
            float pd[4] = {}, ps[4] = {};
            #pragma unroll
            for (int nt = 0; nt < 8; ++nt) {
                const int col = nt * 16 + m;
                const float atd = att[col], ats = att[CH + col];
                #pragma unroll
                for (int r = 0; r < 4; ++r) {
                    pd[r] = fmaf(acc[nt][r], atd, pd[r]);
                    ps[r] = fmaf(acc[nt][r], ats, ps[r]);
                    const int rr = rbase + r;
                    if (rr < n) hb[(size_t)rr * CH + col] = f2bf(acc[nt][r]);
                }
            }
            #pragma unroll
            for (int r = 0; r < 4; ++r) {
                #pragma unroll
                for (int off = 8; off >= 1; off >>= 1) {
                    pd[r] += __shfl_xor(pd[r], off, 64);
                    ps[r] += __shfl_xor(ps[r], off, 64);
                }
                const int rr = rbase + r;
                if (m == 0 && rr < n) { ad[rr] = pd[r]; as_[rr] = ps[r]; }
            }
        }
    } else {
        // ------- SCATTER branch: bin SCHUNK edges into buckets (LDS stash) -------
        int* hist = (int*)smem;                       // 4096 B
        int* cur = hist + NBMAX;                      // 4096 B
        unsigned* rbuf = (unsigned*)(cur + NBMAX);    // 16384 B
        const int e0 = (int)blockIdx.x * SCHUNK;
        for (int t = tid; t < nb; t += 256) hist[t] = 0;
        __syncthreads();
        for (int i = tid; i < SCHUNK; i += 256) {
            const int e = e0 + i;
            if (e < etot) {
                const int d = dst[e];
                rbuf[i] = ((unsigned)d << 16) | (unsigned)src[e];
                atomicAdd(&hist[d >> 6], 1);
            }
        }
        __syncthreads();
        for (int t = tid; t < nb; t += 256) {
            const int h = hist[t];
            cur[t] = h ? atomicAdd(&gcur[t], h) : 0;   // reserve contiguous range
        }
        __syncthreads();
        for (int i = tid; i < SCHUNK; i += 256) {
            const int e = e0 + i;
            if (e < etot) {
                const unsigned r = rbuf[i];
                const int d = (int)(r >> 16);
                const int b = d >> 6;
                const int pos = atomicAdd(&cur[b], 1);
                if (pos < CAP)
                    recs[(size_t)b * CAP + pos] = ((unsigned)(d & 63) << 16) | (r & 0xffffu);
            }
        }
    }
}

// One 512-thread block per bucket. stash+hist -> scan(x8 pad) -> sort -> p=exp(leaky)
// + ssum via LDS float atomics -> pair-gather: dwordx2, 2 edges/instr, 32 lanes/edge.
__global__ __launch_bounds__(512) void aggregate_kernel(const unsigned char* __restrict__ hwb,
                                                        const float* __restrict__ ad,
                                                        const float* __restrict__ as_,
                                                        const int* __restrict__ gcur,
                                                        const unsigned* __restrict__ recs,
                                                        const float* __restrict__ bias,
                                                        float* __restrict__ out, int n) {
    __shared__ alignas(16) unsigned sorted[SCAP];
    __shared__ alignas(16) float alphas[SCAP];
    __shared__ float adl[BNODES];
    __shared__ float ssumL[BNODES];
    __shared__ int cnt[BNODES], ofs[BNODES], cur[BNODES];
    __shared__ int nEp_s;
    const int b = blockIdx.x;
    const int tid = threadIdx.x, lane = tid & 63, wid = tid >> 6;
    const unsigned* br = recs + (size_t)b * CAP;
    int nE = gcur[b]; if (nE > CAP) nE = CAP;
    unsigned* stash = (unsigned*)alphas;

    if (tid < BNODES) {
        cnt[tid] = 0;
        ssumL[tid] = 0.f;
        const int node = b * BNODES + tid;
        adl[tid] = (node < n) ? ad[node] : 0.f;
    }
    __syncthreads();
    for (int i = tid; i < nE; i += 512) {
        const unsigned r = br[i];
        stash[i] = r;
        atomicAdd(&cnt[r >> 16], 1);
    }
    __syncthreads();
    if (wid == 0) {                       // exclusive scan of x8-rounded counts
        const int c = cnt[lane];
        const int cr = (c + 7) & ~7;
        int v = cr;
        #pragma unroll
        for (int off = 1; off < 64; off <<= 1) {
            const int u = __shfl_up(v, (unsigned)off, 64);
            if (lane >= off) v += u;
        }
        ofs[lane] = v - cr;
        cur[lane] = v - cr;
        if (lane == 63) nEp_s = v;
    }
    __syncthreads();
    const int nEp = nEp_s;
    for (int i = tid; i < nEp; i += 512) sorted[i] = SENT;
    __syncthreads();
    for (int i = tid; i < nE; i += 512) {
        const unsigned r = stash[i];
        const int pos = atomicAdd(&cur[r >> 16], 1);
        sorted[pos] = r;
    }
    __syncthreads();
    // p = exp(leaky_relu(ad[dst]+as[src])); rec -> h byte-offset (src*256); pad p=0.
    // ssum accumulated here (per-node LDS atomics) so the gather loop skips it.
    for (int i = tid; i < nEp; i += 512) {   // overwrites stash
        const unsigned r = sorted[i];
        float p = 0.f;
        unsigned so = 0u;
        if (r != SENT) {
            float a = adl[r >> 16] + as_[r & 0xffffu];
            a = (a >= 0.f) ? a : 0.2f * a;
            p = __expf(a);
            so = (r & 0xffffu) << 8;
            atomicAdd(&ssumL[r >> 16], p);
        }
        alphas[i] = p;
        sorted[i] = so;
    }
    __syncthreads();

    // Pair-gather: half = lane>>5 selects even/odd edge of each pair; each load
    // instruction fetches 2 full rows (2 x 32 lanes x 8B). Lane owns 4 channels.
    const unsigned half = (unsigned)(lane >> 5);
    const unsigned lo8 = (unsigned)(lane & 31) * 8u;
    for (int ln = wid; ln < BNODES; ln += 8) {
        const int node = b * BNODES + ln;
        if (node >= n) break;
        const int start = ofs[ln];
        const int cnt8 = (cnt[ln] + 7) & ~7;
        const int end16 = start + (cnt8 & ~15);

        float a0 = 0.f, a1 = 0.f, a2 = 0.f, a3 = 0.f;
        int e = start;
        for (; e < end16; e += 16) {
            const uint4 s0 = *(const uint4*)&sorted[e];
            const uint4 s1 = *(const uint4*)&sorted[e + 4];
            const uint4 s2 = *(const uint4*)&sorted[e + 8];
            const uint4 s3 = *(const uint4*)&sorted[e + 12];
            const float4 p0 = *(const float4*)&alphas[e];
            const float4 p1 = *(const float4*)&alphas[e + 4];
            const float4 p2 = *(const float4*)&alphas[e + 8];
            const float4 p3 = *(const float4*)&alphas[e + 12];
            const unsigned A0 = half ? s0.y : s0.x;
            const unsigned A1 = half ? s0.w : s0.z;
            const unsigned A2 = half ? s1.y : s1.x;
            const unsigned A3 = half ? s1.w : s1.z;
            const unsigned A4 = half ? s2.y : s2.x;
            const unsigned A5 = half ? s2.w : s2.z;
            const unsigned A6 = half ? s3.y : s3.x;
            const unsigned A7 = half ? s3.w : s3.z;
            const float q0 = half ? p0.y : p0.x;
            const float q1 = half ? p0.w : p0.z;
            const float q2 = half ? p1.y : p1.x;
            const float q3 = half ? p1.w : p1.z;
            const float q4 = half ? p2.y : p2.x;
            const float q5 = half ? p2.w : p2.z;
            const float q6 = half ? p3.y : p3.x;
            const float q7 = half ? p3.w : p3.z;
            const uint2 g0 = *(const uint2*)(hwb + A0 + lo8);
            const uint2 g1 = *(const uint2*)(hwb + A1 + lo8);
            const uint2 g2 = *(const uint2*)(hwb + A2 + lo8);
            const uint2 g3 = *(const uint2*)(hwb + A3 + lo8);
            const uint2 g4 = *(const uint2*)(hwb + A4 + lo8);
            const uint2 g5 = *(const uint2*)(hwb + A5 + lo8);
            const uint2 g6 = *(const uint2*)(hwb + A6 + lo8);
            const uint2 g7 = *(const uint2*)(hwb + A7 + lo8);
            a0 = fmaf(q0, __uint_as_float(g0.x << 16), a0);
            a1 = fmaf(q0, __uint_as_float(g0.x & 0xffff0000u), a1);
            a2 = fmaf(q0, __uint_as_float(g0.y << 16), a2);
            a3 = fmaf(q0, __uint_as_float(g0.y & 0xffff0000u), a3);
            a0 = fmaf(q1, __uint_as_float(g1.x << 16), a0);
            a1 = fmaf(q1, __uint_as_float(g1.x & 0xffff0000u), a1);
            a2 = fmaf(q1, __uint_as_float(g1.y << 16), a2);
            a3 = fmaf(q1, __uint_as_float(g1.y & 0xffff0000u), a3);
            a0 = fmaf(q2, __uint_as_float(g2.x << 16), a0);
            a1 = fmaf(q2, __uint_as_float(g2.x & 0xffff0000u), a1);
            a2 = fmaf(q2, __uint_as_float(g2.y << 16), a2);
            a3 = fmaf(q2, __uint_as_float(g2.y & 0xffff0000u), a3);
            a0 = fmaf(q3, __uint_as_float(g3.x << 16), a0);
            a1 = fmaf(q3, __uint_as_float(g3.x & 0xffff0000u), a1);
            a2 = fmaf(q3, __uint_as_float(g3.y << 16), a2);
            a3 = fmaf(q3, __uint_as_float(g3.y & 0xffff0000u), a3);
            a0 = fmaf(q4, __uint_as_float(g4.x << 16), a0);
            a1 = fmaf(q4, __uint_as_float(g4.x & 0xffff0000u), a1);
            a2 = fmaf(q4, __uint_as_float(g4.y << 16), a2);
            a3 = fmaf(q4, __uint_as_float(g4.y & 0xffff0000u), a3);
            a0 = fmaf(q5, __uint_as_float(g5.x << 16), a0);
            a1 = fmaf(q5, __uint_as_float(g5.x & 0xffff0000u), a1);
            a2 = fmaf(q5, __uint_as_float(g5.y << 16), a2);
            a3 = fmaf(q5, __uint_as_float(g5.y & 0xffff0000u), a3);
            a0 = fmaf(q6, __uint_as_float(g6.x << 16), a0);
            a1 = fmaf(q6, __uint_as_float(g6.x & 0xffff0000u), a1);
            a2 = fmaf(q6, __uint_as_float(g6.y << 16), a2);
            a3 = fmaf(q6, __uint_as_float(g6.y & 0xffff0000u), a3);
            a0 = fmaf(q7, __uint_as_float(g7.x << 16), a0);
            a1 = fmaf(q7, __uint_as_float(g7.x & 0xffff0000u), a1);
            a2 = fmaf(q7, __uint_as_float(g7.y << 16), a2);
            a3 = fmaf(q7, __uint_as_float(g7.y & 0xffff0000u), a3);
        }
        if (cnt8 & 8) {   // 8-edge tail: 4 pair-loads
            const uint4 s0 = *(const uint4*)&sorted[e];
            const uint4 s1 = *(const uint4*)&sorted[e + 4];
            const float4 p0 = *(const float4*)&alphas[e];
            const float4 p1 = *(const float4*)&alphas[e + 4];
            const unsigned A0 = half ? s0.y : s0.x;
            const unsigned A1 = half ? s0.w : s0.z;
            const unsigned A2 = half ? s1.y : s1.x;
            const unsigned A3 = half ? s1.w : s1.z;
            const float q0 = half ? p0.y : p0.x;
            const float q1 = half ? p0.w : p0.z;
            const float q2 = half ? p1.y : p1.x;
            const float q3 = half ? p1.w : p1.z;
            const uint2 g0 = *(const uint2*)(hwb + A0 + lo8);
            const uint2 g1 = *(const uint2*)(hwb + A1 + lo8);
            const uint2 g2 = *(const uint2*)(hwb + A2 + lo8);
            const uint2 g3 = *(const uint2*)(hwb + A3 + lo8);
            a0 = fmaf(q0, __uint_as_float(g0.x << 16), a0);
            a1 = fmaf(q0, __uint_as_float(g0.x & 0xffff0000u), a1);
            a2 = fmaf(q0, __uint_as_float(g0.y << 16), a2);
            a3 = fmaf(q0, __uint_as_float(g0.y & 0xffff0000u), a3);
            a0 = fmaf(q1, __uint_as_float(g1.x << 16), a0);
            a1 = fmaf(q1, __uint_as_float(g1.x & 0xffff0000u), a1);
            a2 = fmaf(q1, __uint_as_float(g1.y << 16), a2);
            a3 = fmaf(q1, __uint_as_float(g1.y & 0xffff0000u), a3);
            a0 = fmaf(q2, __uint_as_float(g2.x << 16), a0);
            a1 = fmaf(q2, __uint_as_float(g2.x & 0xffff0000u), a1);
            a2 = fmaf(q2, __uint_as_float(g2.y << 16), a2);
            a3 = fmaf(q2, __uint_as_float(g2.y & 0xffff0000u), a3);
            a0 = fmaf(q3, __uint_as_float(g3.x << 16), a0);
            a1 = fmaf(q3, __uint_as_float(g3.x & 0xffff0000u), a1);
            a2 = fmaf(q3, __uint_as_float(g3.y << 16), a2);
            a3 = fmaf(q3, __uint_as_float(g3.y & 0xffff0000u), a3);
        }
        // combine the two halves (same channels, disjoint edge subsets)
        a0 += __shfl_xor(a0, 32, 64);
        a1 += __shfl_xor(a1, 32, 64);
        a2 += __shfl_xor(a2, 32, 64);
        a3 += __shfl_xor(a3, 32, 64);
        if (lane < 32) {
            const float inv = 1.f / (ssumL[ln] + 1e-16f);
            const float4 bv = *(const float4*)&bias[lane * 4];
            float4 o;
            o.x = fmaf(a0, inv, bv.x);
            o.y = fmaf(a1, inv, bv.y);
            o.z = fmaf(a2, inv, bv.z);
            o.w = fmaf(a3, inv, bv.w);
            *(float4*)&out[node * CH + lane * 4] = o;
        }
    }
}

extern "C" void kernel_launch(void* const* d_in, const int* in_sizes, int n_in,
                              void* d_out, int out_size, void* d_ws, size_t ws_size,
                              hipStream_t stream) {
    const float* x    = (const float*)d_in[0];
    const int*   ei   = (const int*)d_in[1];
    const float* W    = (const float*)d_in[2];
    const float* att  = (const float*)d_in[3];
    const float* bias = (const float*)d_in[4];
    float* out = (float*)d_out;

    const int N_   = in_sizes[0] / CH;   // 50000
    const int Etot = in_sizes[1] / 2;    // 850000
    const int* src = ei;
    const int* dst = ei + Etot;
    const int nb = (N_ + BNODES - 1) / BNODES;        // 782
    const int gb = (N_ + 127) / 128;                  // 391 gemm blocks
    const int sb = (Etot + SCHUNK - 1) / SCHUNK;      // 208 scatter blocks

    char* ws = (char*)d_ws;
    size_t off = 0;
    auto alloc = [&](size_t bytes) -> void* {
        void* p = ws + off;
        off = (off + bytes + 255) & ~(size_t)255;
        return p;
    };
    unsigned short* hb = (unsigned short*)alloc((size_t)N_ * CH * sizeof(unsigned short));
    unsigned short* WT = (unsigned short*)alloc((size_t)CH * WTS * sizeof(unsigned short));
    float* ad      = (float*)alloc((size_t)N_ * sizeof(float));
    float* as_     = (float*)alloc((size_t)N_ * sizeof(float));
    int*   gcur    = (int*)  alloc((size_t)nb * sizeof(int));
    unsigned* recs = (unsigned*)alloc((size_t)nb * CAP * sizeof(unsigned));
    (void)ws_size; (void)n_in; (void)out_size;

    wtzero_kernel<<<8, 256, 0, stream>>>(W, WT, gcur, nb);
    gemm_scatter_kernel<<<sb + gb, 256, 0, stream>>>(x, WT, att, hb, ad, as_,
                                                     src, dst, gcur, recs, N_, Etot, nb, sb);
    aggregate_kernel<<<nb, 512, 0, stream>>>((const unsigned char*)hb, ad, as_, gcur, recs, bias, out, N_);
}